// Round 3
// baseline (358.170 us; speedup 1.0000x reference)
//
#include <hip/hip_runtime.h>
#include <hip/hip_fp16.h>
#include <math.h>

typedef _Float16 f16;
typedef _Float16 f16x8 __attribute__((ext_vector_type(8)));
typedef _Float16 f16x2 __attribute__((ext_vector_type(2)));
typedef float f32x4 __attribute__((ext_vector_type(4)));

__device__ __forceinline__ void gll16(const void* g, void* l) {
  __builtin_amdgcn_global_load_lds((const __attribute__((address_space(1))) void*)g,
                                   (__attribute__((address_space(3))) void*)l, 16, 0, 0);
}

// ---------------- weight packing ----------------
// layout: [tap 9][kc CIN/32][mf MFR][lane 64][j 8], o = mf*16+(lane&15), k = (lane>>4)*8+j
__global__ __launch_bounds__(256) void pack_conv_w(const float* __restrict__ w,
                                                   f16* __restrict__ out,
                                                   int CIN, int MFR, int COUT) {
  int idx = blockIdx.x * 256 + threadIdx.x;
  int KC = CIN / 32;
  int total = 9 * KC * MFR * 64 * 8;
  if (idx >= total) return;
  int j = idx & 7;
  int lane = (idx >> 3) & 63;
  int rest = idx >> 9;
  int mf = rest % MFR; rest /= MFR;
  int kc = rest % KC; int t = rest / KC;
  int oc = mf * 16 + (lane & 15);
  int c = kc * 32 + (lane >> 4) * 8 + j;
  int ky = t / 3, kx = t % 3;
  float v = (oc < COUT) ? w[((oc * CIN + c) * 3 + ky) * 3 + kx] : 0.f;
  out[idx] = (f16)v;
}

// proj: [kc 8][mf 8][lane 64][j 8]
__global__ __launch_bounds__(256) void pack_proj_w(const float* __restrict__ w,
                                                   f16* __restrict__ out) {
  int idx = blockIdx.x * 256 + threadIdx.x;  // 32768
  int j = idx & 7; int lane = (idx >> 3) & 63; int rest = idx >> 9;
  int mf = rest & 7; int kc = rest >> 3;
  int oc = mf * 16 + (lane & 15);
  int c = kc * 32 + (lane >> 4) * 8 + j;
  out[idx] = (f16)w[oc * 256 + c];
}

// ---------------- zero borders of padded cat (384ch) and hid (64ch) ----------------
__global__ __launch_bounds__(256) void k_zero(f16* __restrict__ cat, f16* __restrict__ hid) {
  int idx = blockIdx.x * 256 + threadIdx.x;   // 231168 total
  f16x8 z = {(f16)0, (f16)0, (f16)0, (f16)0, (f16)0, (f16)0, (f16)0, (f16)0};
  int p, b, c8;
  f16* dst; int C;
  if (idx < 198144) {
    c8 = idx % 48; int rest = idx / 48; p = rest % 516; b = rest / 516;
    dst = cat; C = 384;
  } else {
    int i2 = idx - 198144;
    c8 = i2 % 8; int rest = i2 / 8; p = rest % 516; b = rest / 516;
    dst = hid; C = 64;
  }
  int y, x;
  if (p < 130) { y = 0; x = p; }
  else if (p < 260) { y = 129; x = p - 130; }
  else if (p < 388) { y = p - 260 + 1; x = 0; }
  else { y = p - 388 + 1; x = 129; }
  *(f16x8*)&dst[(((size_t)b * 130 + y) * 130 + x) * C + c8 * 8] = z;
}

// ---------------- f_high NCHW -> NHWC f16 ----------------
__global__ __launch_bounds__(256) void k_fhw(const float* __restrict__ fh,
                                             f16* __restrict__ fhw) {
  // grid 4096 = [b 8][y 64][ch2 2][xt 4]
  __shared__ float lds[128 * 17];
  int wg = blockIdx.x;
  int xt = wg & 3; int ch2 = (wg >> 2) & 1; int y = (wg >> 3) & 63; int b = wg >> 9;
  int x0 = xt * 16;
  int tid = threadIdx.x;
  for (int i = 0; i < 8; ++i) {
    int u = i * 256 + tid;          // c(128) x xi(16)
    int c = u >> 4, xi = u & 15;
    lds[c * 17 + xi] = fh[(((size_t)b * 256 + ch2 * 128 + c) * 64 + y) * 64 + x0 + xi];
  }
  __syncthreads();
  {
    int x = tid >> 4, cl = tid & 15;       // 16 x * 16 coct(local)
    f16x8 v;
    #pragma unroll
    for (int j = 0; j < 8; ++j) v[j] = (f16)lds[(cl * 8 + j) * 17 + x];
    int coct = ch2 * 16 + cl;
    *(f16x8*)&fhw[(((size_t)b * 64 + y) * 64 + x0 + x) * 256 + coct * 8] = v;
  }
}

// ---------------- resize -> cat[...,0:256] (padded interior) ----------------
__global__ __launch_bounds__(256) void k_catA(const f16* __restrict__ fhw,
                                              f16* __restrict__ cat) {
  int wg = blockIdx.x;            // [b 8][Y 128]
  int Y = wg & 127, b = wg >> 7;
  float iy = fminf(fmaxf(Y * 0.5f - 0.25f, 0.f), 63.f);
  int y0 = (int)iy; float wy = iy - y0; int y1 = min(y0 + 1, 63);
  int tid = threadIdx.x;
  for (int i = 0; i < 16; ++i) {
    int u = i * 256 + tid; int X = u >> 5, coct = u & 31;
    float ix = fminf(fmaxf(X * 0.5f - 0.25f, 0.f), 63.f);
    int x0 = (int)ix; float wx = ix - x0; int x1 = min(x0 + 1, 63);
    f16x8 v00 = *(const f16x8*)&fhw[(((size_t)b * 64 + y0) * 64 + x0) * 256 + coct * 8];
    f16x8 v01 = *(const f16x8*)&fhw[(((size_t)b * 64 + y0) * 64 + x1) * 256 + coct * 8];
    f16x8 v10 = *(const f16x8*)&fhw[(((size_t)b * 64 + y1) * 64 + x0) * 256 + coct * 8];
    f16x8 v11 = *(const f16x8*)&fhw[(((size_t)b * 64 + y1) * 64 + x1) * 256 + coct * 8];
    f16x8 r;
    #pragma unroll
    for (int j = 0; j < 8; ++j) {
      float t0 = (1.f - wx) * (float)v00[j] + wx * (float)v01[j];
      float t1 = (1.f - wx) * (float)v10[j] + wx * (float)v11[j];
      r[j] = (f16)((1.f - wy) * t0 + wy * t1);
    }
    *(f16x8*)&cat[(((size_t)b * 130 + 1 + Y) * 130 + 1 + X) * 384 + coct * 8] = r;
  }
}

// ---------------- f_low NCHW -> cat[...,256:384] (padded interior) ----------------
__global__ __launch_bounds__(256) void k_catB(const float* __restrict__ fl,
                                              f16* __restrict__ cat) {
  // grid 8192 = [b 8][Y 128][xt 8]
  __shared__ float lds[128 * 17];
  int wg = blockIdx.x;
  int xt = wg & 7; int Y = (wg >> 3) & 127; int b = wg >> 10;
  int x0 = xt * 16; int tid = threadIdx.x;
  for (int i = 0; i < 8; ++i) {
    int u = i * 256 + tid; int c = u >> 4, xi = u & 15;
    lds[c * 17 + xi] = fl[(((size_t)b * 128 + c) * 128 + Y) * 128 + x0 + xi];
  }
  __syncthreads();
  {
    int x = tid >> 4, coct = tid & 15;   // 16 x * 16 coct
    f16x8 v;
    #pragma unroll
    for (int j = 0; j < 8; ++j) v[j] = (f16)lds[(coct * 8 + j) * 17 + x];
    *(f16x8*)&cat[(((size_t)b * 130 + 1 + Y) * 130 + 1 + x0 + x) * 384 + 256 + coct * 8] = v;
  }
}

// ---------------- 3x3 conv, implicit GEMM, padded input, gll-dbuf 2-phase ----------------
// in padded NHWC f16 [B][130][130][CIN]; out NHWC f16 [B][S][S][COUT], S=128+2*OPAD
// tile = (4*NR) rows x 16 cols per WG; wave w owns rows w*NR..w*NR+NR-1 (N_rep=NR).
template<int CIN, int MFR, int COUT, bool RELU, int OPAD, int NR, bool FORCE1>
__global__ __launch_bounds__(256, FORCE1 ? 1 : 2) void k_conv3(const f16* __restrict__ in,
                                                               const f16* __restrict__ apack,
                                                               const float* __restrict__ bias,
                                                               f16* __restrict__ out) {
  constexpr int KC = CIN / 32;
  constexpr int TROWS = 4 * NR;
  constexpr int TY = 128 / TROWS;
  constexpr int NSLOT = (TROWS + 2) * 18 * 4;      // 16B slots per buffer (useful)
  constexpr int NPAD = (NSLOT + 255) & ~255;       // padded to full staging rounds
  constexpr int ROUNDS = NPAD / 256;
  constexpr int PATCH = NPAD * 16;                 // bytes per buffer
  constexpr int EPI = TROWS * 16 * COUT * 2;       // epilogue transpose bytes
  constexpr int LDS_SZ = (2 * PATCH > EPI ? 2 * PATCH : EPI) + (FORCE1 ? 1024 : 0);
  __shared__ __align__(16) char ldsb[LDS_SZ];
  int wg = blockIdx.x;                             // [t][b 8], b = wg&7 -> XCD
  int b = wg & 7; int t = wg >> 3;
  int ty = t % TY, tx = t / TY;
  int y0 = ty * TROWS, x0 = tx * 16;
  int tid = threadIdx.x, lane = tid & 63, w = tid >> 6;
  int lx = lane & 15, hi = lane >> 4;
  int wN = w * NR;

  // per-lane staging source offsets (slot -> swizzled-source channel-oct)
  int ro[ROUNDS];
  #pragma unroll
  for (int j = 0; j < ROUNDS; ++j) {
    int s = j * 256 + w * 64 + lane;
    if (s > NSLOT - 1) s = NSLOT - 1;              // tail lanes: dup source, LDS pad dest
    int p = s >> 2, coct = s & 3;
    int py = p / 18, px = p % 18;
    int cocts = coct ^ ((px >> 1) & 3);
    ro[j] = ((y0 + py) * 130 + (x0 + px)) * CIN + cocts * 8;
  }
  const f16* inb = in + (size_t)b * 130 * 130 * CIN;

  f32x4 acc[MFR][NR];
  #pragma unroll
  for (int m = 0; m < MFR; ++m)
    #pragma unroll
    for (int n = 0; n < NR; ++n) acc[m][n] = (f32x4){0.f, 0.f, 0.f, 0.f};

  auto stage = [&](int kc, int buf) {
    #pragma unroll
    for (int j = 0; j < ROUNDS; ++j)
      gll16(inb + ro[j] + kc * 32, ldsb + buf * PATCH + (j * 256 + w * 64) * 16);
  };

  stage(0, 0);
  __syncthreads();
  for (int kc = 0; kc < KC; ++kc) {
    if (kc + 1 < KC) stage(kc + 1, (kc + 1) & 1);
    const char* cb = ldsb + (kc & 1) * PATCH;
    __builtin_amdgcn_s_setprio(1);
    #pragma unroll
    for (int kx = 0; kx < 3; ++kx) {
      int px = lx + kx;
      int sw = (px >> 1) & 3;
      f16x8 bf[NR + 2];
      #pragma unroll
      for (int s = 0; s < NR + 2; ++s) {
        int slot = ((wN + s) * 18 + px) * 4 + (hi ^ sw);
        bf[s] = *(const f16x8*)(cb + slot * 16);
      }
      #pragma unroll
      for (int ky = 0; ky < 3; ++ky) {
        f16x8 af[MFR];
        #pragma unroll
        for (int m = 0; m < MFR; ++m)
          af[m] = *(const f16x8*)&apack[(size_t)((((ky * 3 + kx) * KC + kc) * MFR + m) * 64 + lane) * 8];
        #pragma unroll
        for (int n = 0; n < NR; ++n)
          #pragma unroll
          for (int m = 0; m < MFR; ++m)
            acc[m][n] = __builtin_amdgcn_mfma_f32_16x16x32_f16(af[m], bf[n + ky], acc[m][n], 0, 0, 0);
      }
    }
    __builtin_amdgcn_s_setprio(0);
    __syncthreads();
  }

  // epilogue: C->LDS (swizzled) -> coalesced NHWC store
  constexpr int S = 128 + 2 * OPAD;
  #pragma unroll
  for (int m = 0; m < MFR; ++m)
    #pragma unroll
    for (int n = 0; n < NR; ++n) {
      int pos = (wN + n) * 16 + lx;
      #pragma unroll
      for (int rp = 0; rp < 2; ++rp) {
        int ch = m * 16 + hi * 4 + rp * 2;
        if (ch < COUT) {
          float v0 = acc[m][n][rp * 2 + 0] + bias[ch];
          float v1 = acc[m][n][rp * 2 + 1] + bias[ch + 1];
          if (RELU) { v0 = fmaxf(v0, 0.f); v1 = fmaxf(v1, 0.f); }
          f16x2 pk; pk[0] = (f16)v0; pk[1] = (f16)v1;
          int addr = ((pos * COUT + ch) * 2) ^ ((pos & 7) << 4);
          *(f16x2*)(ldsb + addr) = pk;
        }
      }
    }
  __syncthreads();
  if constexpr (COUT % 8 == 0) {
    for (int u = tid; u < TROWS * 16 * COUT / 8; u += 256) {
      int pos = u / (COUT / 8); int cp = u % (COUT / 8);
      int addr = ((pos * COUT + cp * 8) * 2) ^ ((pos & 7) << 4);
      f16x8 v = *(const f16x8*)(ldsb + addr);
      int y = y0 + (pos >> 4) + OPAD, x = x0 + (pos & 15) + OPAD;
      *(f16x8*)&out[(((size_t)b * S + y) * S + x) * COUT + cp * 8] = v;
    }
  } else {
    for (int u = tid; u < TROWS * 16 * COUT / 2; u += 256) {
      int pos = u / (COUT / 2); int cp = u % (COUT / 2);
      int addr = ((pos * COUT + cp * 2) * 2) ^ ((pos & 7) << 4);
      f16x2 v = *(const f16x2*)(ldsb + addr);
      int y = y0 + (pos >> 4) + OPAD, x = x0 + (pos & 15) + OPAD;
      *(f16x2*)&out[(((size_t)b * S + y) * S + x) * COUT + cp * 2] = v;
    }
  }
}

// ---------------- grid-sample + proj GEMM + channel partial sums ----------------
__global__ __launch_bounds__(256) void k_gp(const f16* __restrict__ fhw,
                                            const f16* __restrict__ off,
                                            const f16* __restrict__ ppack,
                                            const float* __restrict__ pbias,
                                            f16* __restrict__ x,
                                            float* __restrict__ psum) {
  __shared__ f16 bt[64 * 256];        // 32KB, reused as f32 x-tile then as reduce buf
  __shared__ float4 samp[64];
  char* ldsb = (char*)bt;
  int wg = blockIdx.x;                 // wg = tile*8 + b  (XCD ~ b)
  int b = wg & 7, tile = wg >> 3;
  int pbase = tile * 64;
  int tid = threadIdx.x, lane = tid & 63, w = tid >> 6;
  if (tid < 64) {
    int pos = pbase + tid;
    int yy = pos >> 7, xx = pos & 127;
    float o0 = (float)off[((size_t)b * 16384 + pos) * 2 + 0];
    float o1 = (float)off[((size_t)b * 16384 + pos) * 2 + 1];
    float gx = -1.f + xx * (2.f / 127.f) + o0 * (1.f / 64.f);
    float gy = -1.f + yy * (2.f / 127.f) + o1 * (1.f / 64.f);
    float ix = fminf(fmaxf((gx + 1.f) * 32.f - 0.5f, 0.f), 63.f);
    float iy = fminf(fmaxf((gy + 1.f) * 32.f - 0.5f, 0.f), 63.f);
    float x0f = floorf(ix), y0f = floorf(iy);
    samp[tid] = make_float4(x0f, y0f, ix - x0f, iy - y0f);
  }
  __syncthreads();
  for (int i = 0; i < 8; ++i) {
    int u = i * 256 + tid; int p = u >> 5, coct = u & 31;
    float4 s = samp[p];
    int x0i = (int)s.x, y0i = (int)s.y;
    int x1i = min(x0i + 1, 63), y1i = min(y0i + 1, 63);
    float wx = s.z, wy = s.w;
    const f16* bb = fhw + (size_t)b * 4096 * 256 + coct * 8;
    f16x8 v00 = *(const f16x8*)&bb[(y0i * 64 + x0i) * 256];
    f16x8 v01 = *(const f16x8*)&bb[(y0i * 64 + x1i) * 256];
    f16x8 v10 = *(const f16x8*)&bb[(y1i * 64 + x0i) * 256];
    f16x8 v11 = *(const f16x8*)&bb[(y1i * 64 + x1i) * 256];
    f16x8 r;
    #pragma unroll
    for (int j = 0; j < 8; ++j) {
      float t0 = (1.f - wx) * (float)v00[j] + wx * (float)v01[j];
      float t1 = (1.f - wx) * (float)v10[j] + wx * (float)v11[j];
      r[j] = (f16)((1.f - wy) * t0 + wy * t1);
    }
    int addr = (p * 512 + coct * 16) ^ ((p & 7) << 4);
    *(f16x8*)(ldsb + addr) = r;
  }
  __syncthreads();
  f32x4 acc[2][4];
  #pragma unroll
  for (int m = 0; m < 2; ++m)
    #pragma unroll
    for (int n = 0; n < 4; ++n) acc[m][n] = (f32x4){0.f, 0.f, 0.f, 0.f};
  #pragma unroll
  for (int kc = 0; kc < 8; ++kc) {
    f16x8 af[2];
    #pragma unroll
    for (int m = 0; m < 2; ++m)
      af[m] = *(const f16x8*)&ppack[(size_t)((kc * 8 + w * 2 + m) * 64 + lane) * 8];
    #pragma unroll
    for (int n = 0; n < 4; ++n) {
      int p = n * 16 + (lane & 15);
      int addr = (p * 512 + kc * 64 + ((lane >> 4) * 16)) ^ ((p & 7) << 4);
      f16x8 bf = *(const f16x8*)(ldsb + addr);
      #pragma unroll
      for (int m = 0; m < 2; ++m)
        acc[m][n] = __builtin_amdgcn_mfma_f32_16x16x32_f16(af[m], bf, acc[m][n], 0, 0, 0);
    }
  }
  __syncthreads();
  #pragma unroll
  for (int m = 0; m < 2; ++m)
    #pragma unroll
    for (int n = 0; n < 4; ++n) {
      int p = n * 16 + (lane & 15);
      #pragma unroll
      for (int r = 0; r < 4; ++r) {
        int ch = w * 32 + m * 16 + (lane >> 4) * 4 + r;
        int addr = ((p * 128 + ch) * 4) ^ ((p & 7) << 4);
        *(float*)(ldsb + addr) = acc[m][n][r];
      }
    }
  __syncthreads();
  float part0 = 0.f, part1 = 0.f;
  int cp = tid & 63, wv = tid >> 6;
  int c0 = cp * 2;
  float b0 = pbias[c0], b1 = pbias[c0 + 1];
  #pragma unroll
  for (int i = 0; i < 16; ++i) {
    int p = i * 4 + wv;
    float v0 = *(const float*)(ldsb + (((p * 128 + c0) * 4) ^ ((p & 7) << 4)));
    float v1 = *(const float*)(ldsb + (((p * 128 + c0 + 1) * 4) ^ ((p & 7) << 4)));
    v0 += b0; v1 += b1;
    f16x2 pk; pk[0] = (f16)v0; pk[1] = (f16)v1;
    *(f16x2*)&x[((size_t)b * 16384 + pbase + p) * 128 + c0] = pk;
    part0 += v0; part1 += v1;
  }
  __syncthreads();
  float* rl = (float*)ldsb;
  rl[wv * 128 + c0] = part0; rl[wv * 128 + c0 + 1] = part1;
  __syncthreads();
  if (tid < 128)
    psum[(size_t)wg * 128 + tid] = rl[tid] + rl[128 + tid] + rl[256 + tid] + rl[384 + tid];
}

// ---------------- channel attention ----------------
__global__ __launch_bounds__(128) void k_ca(const float* __restrict__ psum,
                                            const float* __restrict__ w1, const float* __restrict__ b1,
                                            const float* __restrict__ w2, const float* __restrict__ b2,
                                            float* __restrict__ a) {
  __shared__ float pl[128];
  __shared__ float hl[16];
  int b = blockIdx.x; int tid = threadIdx.x;
  float s = 0.f;
  for (int t = 0; t < 256; ++t) s += psum[(size_t)(t * 8 + b) * 128 + tid];
  pl[tid] = s * (1.f / 16384.f);
  __syncthreads();
  if (tid < 16) {
    float h = b1[tid];
    for (int c = 0; c < 128; ++c) h += pl[c] * w1[tid * 128 + c];
    hl[tid] = fmaxf(h, 0.f);
  }
  __syncthreads();
  float z = b2[tid];
  #pragma unroll
  for (int o2 = 0; o2 < 16; ++o2) z += hl[o2] * w2[tid * 16 + o2];
  a[b * 128 + tid] = 1.f / (1.f + expf(-z));
}

// ---------------- per-pixel ch-mean & ch-max of xc (f16 x) ----------------
__global__ __launch_bounds__(256) void k_sm(const f16* __restrict__ x,
                                            const float* __restrict__ a,
                                            float* __restrict__ meanp, float* __restrict__ maxp) {
  __shared__ float al[128];
  int wg = blockIdx.x;
  int pbase = wg * 128;         // global position incl batch
  int b = pbase >> 14;
  int tid = threadIdx.x;
  if (tid < 128) al[tid] = a[b * 128 + tid];
  __syncthreads();
  #pragma unroll
  for (int i = 0; i < 8; ++i) {
    int u = i * 256 + tid;
    int p = u >> 4, q = u & 15;
    f16x8 v = *(const f16x8*)&x[((size_t)pbase + p) * 128 + q * 8];
    float sm = 0.f, mx = -1e30f;
    #pragma unroll
    for (int j = 0; j < 8; ++j) {
      float xc = (float)v[j] * al[q * 8 + j];
      sm += xc; mx = fmaxf(mx, xc);
    }
    #pragma unroll
    for (int d = 1; d < 16; d <<= 1) {
      sm += __shfl_xor(sm, d);
      mx = fmaxf(mx, __shfl_xor(mx, d));
    }
    if ((tid & 15) == 0) {
      meanp[pbase + p] = sm * (1.f / 128.f);
      maxp[pbase + p] = mx;
    }
  }
}

// ---------------- 7x7 spatial-attention conv + sigmoid ----------------
__global__ __launch_bounds__(256) void k_sa(const float* __restrict__ meanp,
                                            const float* __restrict__ maxp,
                                            const float* __restrict__ sw, const float* __restrict__ sb,
                                            float* __restrict__ sap) {
  __shared__ float lds[2][22][22];
  __shared__ float wl[98];
  int wg = blockIdx.x;             // [b 8][ty 8][tx 8]
  int tx = wg & 7, ty = (wg >> 3) & 7, b = wg >> 6;
  int y0 = ty * 16, x0 = tx * 16;
  int tid = threadIdx.x;
  if (tid < 98) wl[tid] = sw[tid];
  for (int u = tid; u < 2 * 22 * 22; u += 256) {
    int ch = u / 484; int p = u % 484; int py = p / 22, px = p % 22;
    int gy = y0 + py - 3, gx = x0 + px - 3;
    float v = 0.f;
    if (gy >= 0 && gy < 128 && gx >= 0 && gx < 128)
      v = ch ? maxp[(size_t)b * 16384 + gy * 128 + gx] : meanp[(size_t)b * 16384 + gy * 128 + gx];
    lds[ch][py][px] = v;
  }
  __syncthreads();
  int py = tid >> 4, px = tid & 15;
  float accv = sb[0];
  #pragma unroll
  for (int ch = 0; ch < 2; ++ch)
    for (int ky = 0; ky < 7; ++ky)
      #pragma unroll
      for (int kx = 0; kx < 7; ++kx)
        accv += lds[ch][py + ky][px + kx] * wl[ch * 49 + ky * 7 + kx];
  sap[(size_t)b * 16384 + (y0 + py) * 128 + x0 + px] = 1.f / (1.f + expf(-accv));
}

// ---------------- final: out NCHW = x * a * sa (f16 x, NHWC->NCHW) ----------------
__global__ __launch_bounds__(256) void k_out(const f16* __restrict__ x,
                                             const float* __restrict__ a,
                                             const float* __restrict__ sap,
                                             float* __restrict__ out) {
  __shared__ float lds[32 * 129];
  __shared__ float al[128];
  __shared__ float sl[32];
  int wg = blockIdx.x;
  int pbase = wg * 32; int b = pbase >> 14;
  int tid = threadIdx.x;
  if (tid < 128) al[tid] = a[b * 128 + tid];
  if (tid < 32) sl[tid] = sap[pbase + tid];
  __syncthreads();
  #pragma unroll
  for (int i = 0; i < 2; ++i) {
    int u = i * 256 + tid;
    int p = u >> 4, q = u & 15;
    f16x8 v = *(const f16x8*)&x[((size_t)pbase + p) * 128 + q * 8];
    #pragma unroll
    for (int j = 0; j < 8; ++j) lds[p * 129 + q * 8 + j] = (float)v[j];
  }
  __syncthreads();
  #pragma unroll
  for (int i = 0; i < 16; ++i) {
    int u = i * 256 + tid; int c = u >> 5, p = u & 31;
    float v = lds[p * 129 + c] * al[c] * sl[p];
    out[((size_t)(b * 128 + c)) * 16384 + (pbase & 16383) + p] = v;
  }
}

// ---------------- launcher ----------------
extern "C" void kernel_launch(void* const* d_in, const int* in_sizes, int n_in,
                              void* d_out, int out_size, void* d_ws, size_t ws_size,
                              hipStream_t stream) {
  const float* f_high = (const float*)d_in[0];
  const float* f_low  = (const float*)d_in[1];
  const float* off_w1 = (const float*)d_in[2];
  const float* off_b1 = (const float*)d_in[3];
  const float* off_w2 = (const float*)d_in[4];
  const float* off_b2 = (const float*)d_in[5];
  const float* proj_w = (const float*)d_in[6];
  const float* proj_b = (const float*)d_in[7];
  const float* ca_w1  = (const float*)d_in[8];
  const float* ca_b1  = (const float*)d_in[9];
  const float* ca_w2  = (const float*)d_in[10];
  const float* ca_b2  = (const float*)d_in[11];
  const float* sa_w   = (const float*)d_in[12];
  const float* sa_b   = (const float*)d_in[13];
  float* out = (float*)d_out;

  char* ws = (char*)d_ws; size_t o = 0;
  auto alloc = [&](size_t b) { char* p = ws + o; o += (b + 255) & ~(size_t)255; return p; };
  f16*   fhw  = (f16*)alloc(8ull * 4096 * 256 * 2);        // f_high NHWC f16
  f16*   cat  = (f16*)alloc(8ull * 130 * 130 * 384 * 2);   // concat NHWC f16, padded
  f16*   hid  = (f16*)alloc(8ull * 130 * 130 * 64 * 2);    // conv1 out NHWC f16, padded
  f16*   offb = (f16*)alloc(8ull * 16384 * 2 * 2);         // conv2 out NHWC f16
  f16*   ap1  = (f16*)alloc(221184ull * 2);                // packed off_w1
  f16*   ap2  = (f16*)alloc(9216ull * 2);                  // packed off_w2
  f16*   pp   = (f16*)alloc(32768ull * 2);                 // packed proj_w
  f16*   xbuf = (f16*)alloc(8ull * 16384 * 128 * 2);       // proj out NHWC f16
  float* ps   = (float*)alloc(2048ull * 128 * 4);          // per-WG channel partial sums
  float* av   = (float*)alloc(8ull * 128 * 4);             // channel attention
  float* mp   = (float*)alloc(131072ull * 4);              // ch-mean plane
  float* xp   = (float*)alloc(131072ull * 4);              // ch-max plane
  float* sp   = (float*)alloc(131072ull * 4);              // spatial attention

  pack_conv_w<<<864, 256, 0, stream>>>(off_w1, ap1, 384, 4, 64);
  pack_conv_w<<<36, 256, 0, stream>>>(off_w2, ap2, 64, 1, 2);
  pack_proj_w<<<128, 256, 0, stream>>>(proj_w, pp);
  k_zero<<<903, 256, 0, stream>>>(cat, hid);
  k_fhw<<<4096, 256, 0, stream>>>(f_high, fhw);
  k_catA<<<1024, 256, 0, stream>>>(fhw, cat);
  k_catB<<<8192, 256, 0, stream>>>(f_low, cat);
  // conv1: 32x16 tile, NR=8, 1 WG/CU, grid [t 32][b 8]
  k_conv3<384, 4, 64, true, 1, 8, true><<<256, 256, 0, stream>>>(cat, ap1, off_b1, hid);
  // conv2: 16x16 tile, NR=4, 2 WG/CU, grid [t 64][b 8]
  k_conv3<64, 1, 2, false, 0, 4, false><<<512, 256, 0, stream>>>(hid, ap2, off_b2, offb);
  k_gp<<<2048, 256, 0, stream>>>(fhw, offb, pp, proj_b, xbuf, ps);
  k_ca<<<8, 128, 0, stream>>>(ps, ca_w1, ca_b1, ca_w2, ca_b2, av);
  k_sm<<<1024, 256, 0, stream>>>(xbuf, av, mp, xp);
  k_sa<<<512, 256, 0, stream>>>(mp, xp, sa_w, sa_b, sp);
  k_out<<<4096, 256, 0, stream>>>(xbuf, av, sp, out);
}

// Round 4
// 327.713 us; speedup vs baseline: 1.0929x; 1.0929x over previous
//
#include <hip/hip_runtime.h>
#include <hip/hip_fp16.h>
#include <math.h>

typedef _Float16 f16;
typedef _Float16 f16x8 __attribute__((ext_vector_type(8)));
typedef _Float16 f16x2 __attribute__((ext_vector_type(2)));
typedef float f32x4 __attribute__((ext_vector_type(4)));

__device__ __forceinline__ void gll16(const void* g, void* l) {
  __builtin_amdgcn_global_load_lds((const __attribute__((address_space(1))) void*)g,
                                   (__attribute__((address_space(3))) void*)l, 16, 0, 0);
}

// ================= prep: pack weights (kc-outermost), zero pad borders, f_high->NHWC =================
// pack layout: [kc KC][tap 9][mf MFR][lane 64][j 8], o = mf*16+(lane&15), k = (lane>>4)*8+j
__device__ __forceinline__ void pack_conv_body(int idx, const float* __restrict__ w,
                                               f16* __restrict__ out, int CIN, int MFR, int COUT) {
  int KC = CIN / 32;
  int total = 9 * KC * MFR * 64 * 8;
  if (idx >= total) return;
  int j = idx & 7;
  int lane = (idx >> 3) & 63;
  int rest = idx >> 9;
  int mf = rest % MFR; rest /= MFR;
  int t = rest % 9; int kc = rest / 9;
  int oc = mf * 16 + (lane & 15);
  int c = kc * 32 + (lane >> 4) * 8 + j;
  int ky = t / 3, kx = t % 3;
  float v = (oc < COUT) ? w[((oc * CIN + c) * 3 + ky) * 3 + kx] : 0.f;
  out[idx] = (f16)v;
}

__global__ __launch_bounds__(256) void k_prep(const float* __restrict__ off_w1, f16* __restrict__ ap1,
                                              const float* __restrict__ off_w2, f16* __restrict__ ap2,
                                              const float* __restrict__ proj_w, f16* __restrict__ pp,
                                              f16* __restrict__ cat, f16* __restrict__ hid,
                                              const float* __restrict__ fh, f16* __restrict__ fhw) {
  int blk = blockIdx.x;
  int tid = threadIdx.x;
  if (blk < 864) {                       // pack conv1 weights
    pack_conv_body(blk * 256 + tid, off_w1, ap1, 384, 4, 64);
    return;
  }
  blk -= 864;
  if (blk < 36) {                        // pack conv2 weights
    pack_conv_body(blk * 256 + tid, off_w2, ap2, 64, 1, 2);
    return;
  }
  blk -= 36;
  if (blk < 128) {                       // pack proj: [kc 8][mf 8][lane 64][j 8]
    int idx = blk * 256 + tid;
    int j = idx & 7; int lane = (idx >> 3) & 63; int rest = idx >> 9;
    int mf = rest & 7; int kc = rest >> 3;
    int oc = mf * 16 + (lane & 15);
    int c = kc * 32 + (lane >> 4) * 8 + j;
    pp[idx] = (f16)proj_w[oc * 256 + c];
    return;
  }
  blk -= 128;
  if (blk < 903) {                       // zero pad borders of cat & hid
    int idx = blk * 256 + tid;
    if (idx >= 231168) return;
    f16x8 z = {(f16)0, (f16)0, (f16)0, (f16)0, (f16)0, (f16)0, (f16)0, (f16)0};
    int p, b, c8;
    f16* dst; int C;
    if (idx < 198144) {
      c8 = idx % 48; int rest = idx / 48; p = rest % 516; b = rest / 516;
      dst = cat; C = 384;
    } else {
      int i2 = idx - 198144;
      c8 = i2 % 8; int rest = i2 / 8; p = rest % 516; b = rest / 516;
      dst = hid; C = 64;
    }
    int y, x;
    if (p < 130) { y = 0; x = p; }
    else if (p < 260) { y = 129; x = p - 130; }
    else if (p < 388) { y = p - 260 + 1; x = 0; }
    else { y = p - 388 + 1; x = 129; }
    *(f16x8*)&dst[(((size_t)b * 130 + y) * 130 + x) * C + c8 * 8] = z;
    return;
  }
  blk -= 903;
  {                                      // f_high NCHW -> NHWC f16; blk = [b 8][y 64][ch2 2][xt 4]
    __shared__ float lds[128 * 17];
    int xt = blk & 3; int ch2 = (blk >> 2) & 1; int y = (blk >> 3) & 63; int b = blk >> 9;
    int x0 = xt * 16;
    for (int i = 0; i < 8; ++i) {
      int u = i * 256 + tid;
      int c = u >> 4, xi = u & 15;
      lds[c * 17 + xi] = fh[(((size_t)b * 256 + ch2 * 128 + c) * 64 + y) * 64 + x0 + xi];
    }
    __syncthreads();
    int x = tid >> 4, cl = tid & 15;
    f16x8 v;
    #pragma unroll
    for (int j = 0; j < 8; ++j) v[j] = (f16)lds[(cl * 8 + j) * 17 + x];
    int coct = ch2 * 16 + cl;
    *(f16x8*)&fhw[(((size_t)b * 64 + y) * 64 + x0 + x) * 256 + coct * 8] = v;
  }
}

// ================= cat: resize f_high (ch 0..255) + transpose f_low (ch 256..383) =================
__global__ __launch_bounds__(256) void k_cat(const f16* __restrict__ fhw,
                                             const float* __restrict__ fl,
                                             f16* __restrict__ cat) {
  int blk = blockIdx.x;
  int tid = threadIdx.x;
  if (blk < 1024) {                      // resize: [b 8][Y 128]
    int Y = blk & 127, b = blk >> 7;
    float iy = fminf(fmaxf(Y * 0.5f - 0.25f, 0.f), 63.f);
    int y0 = (int)iy; float wy = iy - y0; int y1 = min(y0 + 1, 63);
    for (int i = 0; i < 16; ++i) {
      int u = i * 256 + tid; int X = u >> 5, coct = u & 31;
      float ix = fminf(fmaxf(X * 0.5f - 0.25f, 0.f), 63.f);
      int x0 = (int)ix; float wx = ix - x0; int x1 = min(x0 + 1, 63);
      f16x8 v00 = *(const f16x8*)&fhw[(((size_t)b * 64 + y0) * 64 + x0) * 256 + coct * 8];
      f16x8 v01 = *(const f16x8*)&fhw[(((size_t)b * 64 + y0) * 64 + x1) * 256 + coct * 8];
      f16x8 v10 = *(const f16x8*)&fhw[(((size_t)b * 64 + y1) * 64 + x0) * 256 + coct * 8];
      f16x8 v11 = *(const f16x8*)&fhw[(((size_t)b * 64 + y1) * 64 + x1) * 256 + coct * 8];
      f16x8 r;
      #pragma unroll
      for (int j = 0; j < 8; ++j) {
        float t0 = (1.f - wx) * (float)v00[j] + wx * (float)v01[j];
        float t1 = (1.f - wx) * (float)v10[j] + wx * (float)v11[j];
        r[j] = (f16)((1.f - wy) * t0 + wy * t1);
      }
      *(f16x8*)&cat[(((size_t)b * 130 + 1 + Y) * 130 + 1 + X) * 384 + coct * 8] = r;
    }
    return;
  }
  blk -= 1024;
  {                                      // f_low transpose: [b 8][Y 128][xt 8]
    __shared__ float lds[128 * 17];
    int xt = blk & 7; int Y = (blk >> 3) & 127; int b = blk >> 10;
    int x0 = xt * 16;
    for (int i = 0; i < 8; ++i) {
      int u = i * 256 + tid; int c = u >> 4, xi = u & 15;
      lds[c * 17 + xi] = fl[(((size_t)b * 128 + c) * 128 + Y) * 128 + x0 + xi];
    }
    __syncthreads();
    int x = tid >> 4, coct = tid & 15;
    f16x8 v;
    #pragma unroll
    for (int j = 0; j < 8; ++j) v[j] = (f16)lds[(coct * 8 + j) * 17 + x];
    *(f16x8*)&cat[(((size_t)b * 130 + 1 + Y) * 130 + 1 + x0 + x) * 384 + 256 + coct * 8] = v;
  }
}

// ================= conv1: 3x3 384->64, mf-split NR=8 implicit GEMM =================
// tile 16x16 per WG (4 waves); wave w: mfh=w&1 (32 out-ch), rh=w>>1 (rows rh*8..+7)
__global__ __launch_bounds__(256) void k_conv1(const f16* __restrict__ in,
                                               const f16* __restrict__ apack,
                                               const float* __restrict__ bias,
                                               f16* __restrict__ out) {
  constexpr int KC = 12;
  constexpr int NSLOT = 1296;            // 18*18*4 16B slots
  constexpr int PATCH = 1536 * 16;       // padded to 6 staging rounds
  __shared__ __align__(16) char ldsb[2 * PATCH];
  int wg = blockIdx.x;                   // [t 64][b 8]
  int b = wg & 7; int t = wg >> 3;
  int ty = t & 7, tx = t >> 3;
  int y0 = ty * 16, x0 = tx * 16;
  int tid = threadIdx.x, lane = tid & 63, w = tid >> 6;
  int lx = lane & 15, hi = lane >> 4;
  int mfh = w & 1, rbase = (w >> 1) * 8;

  int ro[6];
  #pragma unroll
  for (int j = 0; j < 6; ++j) {
    int s = j * 256 + tid;
    if (s > NSLOT - 1) s = NSLOT - 1;
    int p = s >> 2, coct = s & 3;
    int py = p / 18, px = p % 18;
    int cocts = coct ^ ((px >> 1) & 3);
    ro[j] = ((y0 + py) * 130 + (x0 + px)) * 384 + cocts * 8;
  }
  const f16* inb = in + (size_t)b * 130 * 130 * 384;

  f32x4 acc[2][8];
  #pragma unroll
  for (int m = 0; m < 2; ++m)
    #pragma unroll
    for (int n = 0; n < 8; ++n) acc[m][n] = (f32x4){0.f, 0.f, 0.f, 0.f};

  auto stage = [&](int kc, int buf) {
    #pragma unroll
    for (int j = 0; j < 6; ++j)
      gll16(inb + ro[j] + kc * 32, ldsb + buf * PATCH + (j * 256 + tid) * 16);
  };

  stage(0, 0);
  __syncthreads();
  for (int kc = 0; kc < KC; ++kc) {
    if (kc + 1 < KC) stage(kc + 1, (kc + 1) & 1);
    const char* cb = ldsb + (kc & 1) * PATCH;
    __builtin_amdgcn_s_setprio(1);
    #pragma unroll
    for (int kx = 0; kx < 3; ++kx) {
      int px = lx + kx;
      int sw = (px >> 1) & 3;
      f16x8 bf[10];
      #pragma unroll
      for (int s = 0; s < 10; ++s) {
        int slot = ((rbase + s) * 18 + px) * 4 + (hi ^ sw);
        bf[s] = *(const f16x8*)(cb + slot * 16);
      }
      #pragma unroll
      for (int ky = 0; ky < 3; ++ky) {
        f16x8 af[2];
        #pragma unroll
        for (int m = 0; m < 2; ++m)
          af[m] = *(const f16x8*)&apack[(size_t)(((kc * 9 + ky * 3 + kx) * 4 + mfh * 2 + m) * 64 + lane) * 8];
        #pragma unroll
        for (int n = 0; n < 8; ++n)
          #pragma unroll
          for (int m = 0; m < 2; ++m)
            acc[m][n] = __builtin_amdgcn_mfma_f32_16x16x32_f16(af[m], bf[n + ky], acc[m][n], 0, 0, 0);
      }
    }
    __builtin_amdgcn_s_setprio(0);
    __syncthreads();
  }

  // epilogue: C->LDS (swizzled) -> coalesced padded-NHWC store
  #pragma unroll
  for (int m = 0; m < 2; ++m)
    #pragma unroll
    for (int n = 0; n < 8; ++n) {
      int pos = (rbase + n) * 16 + lx;
      #pragma unroll
      for (int rp = 0; rp < 2; ++rp) {
        int ch = mfh * 32 + m * 16 + hi * 4 + rp * 2;
        float v0 = fmaxf(acc[m][n][rp * 2 + 0] + bias[ch], 0.f);
        float v1 = fmaxf(acc[m][n][rp * 2 + 1] + bias[ch + 1], 0.f);
        f16x2 pk; pk[0] = (f16)v0; pk[1] = (f16)v1;
        int addr = ((pos * 64 + ch) * 2) ^ ((pos & 7) << 4);
        *(f16x2*)(ldsb + addr) = pk;
      }
    }
  __syncthreads();
  #pragma unroll
  for (int i = 0; i < 8; ++i) {
    int u = i * 256 + tid;
    int pos = u >> 3, cp = u & 7;
    int addr = ((pos * 64 + cp * 8) * 2) ^ ((pos & 7) << 4);
    f16x8 v = *(const f16x8*)(ldsb + addr);
    int y = y0 + (pos >> 4) + 1, x = x0 + (pos & 15) + 1;
    *(f16x8*)&out[(((size_t)b * 130 + y) * 130 + x) * 64 + cp * 8] = v;
  }
}

// ================= conv2: 3x3 64->2 (generic small template) =================
template<int CIN, int MFR, int COUT, bool RELU, int OPAD, int NR>
__global__ __launch_bounds__(256, 2) void k_conv3(const f16* __restrict__ in,
                                                  const f16* __restrict__ apack,
                                                  const float* __restrict__ bias,
                                                  f16* __restrict__ out) {
  constexpr int KC = CIN / 32;
  constexpr int TROWS = 4 * NR;
  constexpr int TY = 128 / TROWS;
  constexpr int NSLOT = (TROWS + 2) * 18 * 4;
  constexpr int NPAD = (NSLOT + 255) & ~255;
  constexpr int ROUNDS = NPAD / 256;
  constexpr int PATCH = NPAD * 16;
  constexpr int EPI = TROWS * 16 * COUT * 2;
  constexpr int LDS_SZ = (2 * PATCH > EPI ? 2 * PATCH : EPI);
  __shared__ __align__(16) char ldsb[LDS_SZ];
  int wg = blockIdx.x;
  int b = wg & 7; int t = wg >> 3;
  int ty = t % TY, tx = t / TY;
  int y0 = ty * TROWS, x0 = tx * 16;
  int tid = threadIdx.x, lane = tid & 63, w = tid >> 6;
  int lx = lane & 15, hi = lane >> 4;
  int wN = w * NR;

  int ro[ROUNDS];
  #pragma unroll
  for (int j = 0; j < ROUNDS; ++j) {
    int s = j * 256 + tid;
    if (s > NSLOT - 1) s = NSLOT - 1;
    int p = s >> 2, coct = s & 3;
    int py = p / 18, px = p % 18;
    int cocts = coct ^ ((px >> 1) & 3);
    ro[j] = ((y0 + py) * 130 + (x0 + px)) * CIN + cocts * 8;
  }
  const f16* inb = in + (size_t)b * 130 * 130 * CIN;

  f32x4 acc[MFR][NR];
  #pragma unroll
  for (int m = 0; m < MFR; ++m)
    #pragma unroll
    for (int n = 0; n < NR; ++n) acc[m][n] = (f32x4){0.f, 0.f, 0.f, 0.f};

  auto stage = [&](int kc, int buf) {
    #pragma unroll
    for (int j = 0; j < ROUNDS; ++j)
      gll16(inb + ro[j] + kc * 32, ldsb + buf * PATCH + (j * 256 + tid) * 16);
  };

  stage(0, 0);
  __syncthreads();
  for (int kc = 0; kc < KC; ++kc) {
    if (kc + 1 < KC) stage(kc + 1, (kc + 1) & 1);
    const char* cb = ldsb + (kc & 1) * PATCH;
    __builtin_amdgcn_s_setprio(1);
    #pragma unroll
    for (int kx = 0; kx < 3; ++kx) {
      int px = lx + kx;
      int sw = (px >> 1) & 3;
      f16x8 bf[NR + 2];
      #pragma unroll
      for (int s = 0; s < NR + 2; ++s) {
        int slot = ((wN + s) * 18 + px) * 4 + (hi ^ sw);
        bf[s] = *(const f16x8*)(cb + slot * 16);
      }
      #pragma unroll
      for (int ky = 0; ky < 3; ++ky) {
        f16x8 af[MFR];
        #pragma unroll
        for (int m = 0; m < MFR; ++m)
          af[m] = *(const f16x8*)&apack[(size_t)(((kc * 9 + ky * 3 + kx) * MFR + m) * 64 + lane) * 8];
        #pragma unroll
        for (int n = 0; n < NR; ++n)
          #pragma unroll
          for (int m = 0; m < MFR; ++m)
            acc[m][n] = __builtin_amdgcn_mfma_f32_16x16x32_f16(af[m], bf[n + ky], acc[m][n], 0, 0, 0);
      }
    }
    __builtin_amdgcn_s_setprio(0);
    __syncthreads();
  }

  constexpr int S = 128 + 2 * OPAD;
  #pragma unroll
  for (int m = 0; m < MFR; ++m)
    #pragma unroll
    for (int n = 0; n < NR; ++n) {
      int pos = (wN + n) * 16 + lx;
      #pragma unroll
      for (int rp = 0; rp < 2; ++rp) {
        int ch = m * 16 + hi * 4 + rp * 2;
        if (ch < COUT) {
          float v0 = acc[m][n][rp * 2 + 0] + bias[ch];
          float v1 = acc[m][n][rp * 2 + 1] + bias[ch + 1];
          if (RELU) { v0 = fmaxf(v0, 0.f); v1 = fmaxf(v1, 0.f); }
          f16x2 pk; pk[0] = (f16)v0; pk[1] = (f16)v1;
          int addr = ((pos * COUT + ch) * 2) ^ ((pos & 7) << 4);
          *(f16x2*)(ldsb + addr) = pk;
        }
      }
    }
  __syncthreads();
  for (int u = tid; u < TROWS * 16 * COUT / 2; u += 256) {
    int pos = u / (COUT / 2); int cp = u % (COUT / 2);
    int addr = ((pos * COUT + cp * 2) * 2) ^ ((pos & 7) << 4);
    f16x2 v = *(const f16x2*)(ldsb + addr);
    int y = y0 + (pos >> 4) + OPAD, x = x0 + (pos & 15) + OPAD;
    *(f16x2*)&out[(((size_t)b * S + y) * S + x) * COUT + cp * 2] = v;
  }
}

// ================= grid-sample + proj GEMM + channel partial sums =================
__global__ __launch_bounds__(256) void k_gp(const f16* __restrict__ fhw,
                                            const f16* __restrict__ off,
                                            const f16* __restrict__ ppack,
                                            const float* __restrict__ pbias,
                                            f16* __restrict__ x,
                                            float* __restrict__ psum) {
  __shared__ f16 bt[64 * 256];
  __shared__ float4 samp[64];
  char* ldsb = (char*)bt;
  int wg = blockIdx.x;                 // wg = tile*8 + b  (XCD ~ b)
  int b = wg & 7, tile = wg >> 3;
  int pbase = tile * 64;
  int tid = threadIdx.x, lane = tid & 63, w = tid >> 6;
  if (tid < 64) {
    int pos = pbase + tid;
    int yy = pos >> 7, xx = pos & 127;
    float o0 = (float)off[((size_t)b * 16384 + pos) * 2 + 0];
    float o1 = (float)off[((size_t)b * 16384 + pos) * 2 + 1];
    float gx = -1.f + xx * (2.f / 127.f) + o0 * (1.f / 64.f);
    float gy = -1.f + yy * (2.f / 127.f) + o1 * (1.f / 64.f);
    float ix = fminf(fmaxf((gx + 1.f) * 32.f - 0.5f, 0.f), 63.f);
    float iy = fminf(fmaxf((gy + 1.f) * 32.f - 0.5f, 0.f), 63.f);
    float x0f = floorf(ix), y0f = floorf(iy);
    samp[tid] = make_float4(x0f, y0f, ix - x0f, iy - y0f);
  }
  __syncthreads();
  for (int i = 0; i < 8; ++i) {
    int u = i * 256 + tid; int p = u >> 5, coct = u & 31;
    float4 s = samp[p];
    int x0i = (int)s.x, y0i = (int)s.y;
    int x1i = min(x0i + 1, 63), y1i = min(y0i + 1, 63);
    float wx = s.z, wy = s.w;
    const f16* bb = fhw + (size_t)b * 4096 * 256 + coct * 8;
    f16x8 v00 = *(const f16x8*)&bb[(y0i * 64 + x0i) * 256];
    f16x8 v01 = *(const f16x8*)&bb[(y0i * 64 + x1i) * 256];
    f16x8 v10 = *(const f16x8*)&bb[(y1i * 64 + x0i) * 256];
    f16x8 v11 = *(const f16x8*)&bb[(y1i * 64 + x1i) * 256];
    f16x8 r;
    #pragma unroll
    for (int j = 0; j < 8; ++j) {
      float t0 = (1.f - wx) * (float)v00[j] + wx * (float)v01[j];
      float t1 = (1.f - wx) * (float)v10[j] + wx * (float)v11[j];
      r[j] = (f16)((1.f - wy) * t0 + wy * t1);
    }
    int addr = (p * 512 + coct * 16) ^ ((p & 7) << 4);
    *(f16x8*)(ldsb + addr) = r;
  }
  __syncthreads();
  f32x4 acc[2][4];
  #pragma unroll
  for (int m = 0; m < 2; ++m)
    #pragma unroll
    for (int n = 0; n < 4; ++n) acc[m][n] = (f32x4){0.f, 0.f, 0.f, 0.f};
  #pragma unroll
  for (int kc = 0; kc < 8; ++kc) {
    f16x8 af[2];
    #pragma unroll
    for (int m = 0; m < 2; ++m)
      af[m] = *(const f16x8*)&ppack[(size_t)((kc * 8 + w * 2 + m) * 64 + lane) * 8];
    #pragma unroll
    for (int n = 0; n < 4; ++n) {
      int p = n * 16 + (lane & 15);
      int addr = (p * 512 + kc * 64 + ((lane >> 4) * 16)) ^ ((p & 7) << 4);
      f16x8 bf = *(const f16x8*)(ldsb + addr);
      #pragma unroll
      for (int m = 0; m < 2; ++m)
        acc[m][n] = __builtin_amdgcn_mfma_f32_16x16x32_f16(af[m], bf, acc[m][n], 0, 0, 0);
    }
  }
  __syncthreads();
  #pragma unroll
  for (int m = 0; m < 2; ++m)
    #pragma unroll
    for (int n = 0; n < 4; ++n) {
      int p = n * 16 + (lane & 15);
      #pragma unroll
      for (int r = 0; r < 4; ++r) {
        int ch = w * 32 + m * 16 + (lane >> 4) * 4 + r;
        int addr = ((p * 128 + ch) * 4) ^ ((p & 7) << 4);
        *(float*)(ldsb + addr) = acc[m][n][r];
      }
    }
  __syncthreads();
  float part0 = 0.f, part1 = 0.f;
  int cp = tid & 63, wv = tid >> 6;
  int c0 = cp * 2;
  float b0 = pbias[c0], b1 = pbias[c0 + 1];
  #pragma unroll
  for (int i = 0; i < 16; ++i) {
    int p = i * 4 + wv;
    float v0 = *(const float*)(ldsb + (((p * 128 + c0) * 4) ^ ((p & 7) << 4)));
    float v1 = *(const float*)(ldsb + (((p * 128 + c0 + 1) * 4) ^ ((p & 7) << 4)));
    v0 += b0; v1 += b1;
    f16x2 pk; pk[0] = (f16)v0; pk[1] = (f16)v1;
    *(f16x2*)&x[((size_t)b * 16384 + pbase + p) * 128 + c0] = pk;
    part0 += v0; part1 += v1;
  }
  __syncthreads();
  float* rl = (float*)ldsb;
  rl[wv * 128 + c0] = part0; rl[wv * 128 + c0 + 1] = part1;
  __syncthreads();
  if (tid < 128)
    psum[(size_t)wg * 128 + tid] = rl[tid] + rl[128 + tid] + rl[256 + tid] + rl[384 + tid];
}

// ================= channel attention (coalesced reduction) =================
__global__ __launch_bounds__(256) void k_ca(const float* __restrict__ psum,
                                            const float* __restrict__ w1, const float* __restrict__ b1,
                                            const float* __restrict__ w2, const float* __restrict__ b2,
                                            float* __restrict__ a) {
  __shared__ float red[256];
  __shared__ float pl[128];
  __shared__ float hl[16];
  int b = blockIdx.x; int tid = threadIdx.x;
  int half = tid >> 7, c = tid & 127;
  float s = 0.f;
  for (int i = 0; i < 128; ++i)
    s += psum[(size_t)((i * 2 + half) * 8 + b) * 128 + c];
  red[tid] = s;
  __syncthreads();
  if (tid < 128) pl[tid] = (red[tid] + red[tid + 128]) * (1.f / 16384.f);
  __syncthreads();
  if (tid < 16) {
    float h = b1[tid];
    for (int cc = 0; cc < 128; ++cc) h += pl[cc] * w1[tid * 128 + cc];
    hl[tid] = fmaxf(h, 0.f);
  }
  __syncthreads();
  if (tid < 128) {
    float z = b2[tid];
    #pragma unroll
    for (int o2 = 0; o2 < 16; ++o2) z += hl[o2] * w2[tid * 16 + o2];
    a[b * 128 + tid] = 1.f / (1.f + expf(-z));
  }
}

// ================= per-pixel ch-mean & ch-max of xc =================
__global__ __launch_bounds__(256) void k_sm(const f16* __restrict__ x,
                                            const float* __restrict__ a,
                                            float* __restrict__ meanp, float* __restrict__ maxp) {
  __shared__ float al[128];
  int wg = blockIdx.x;
  int pbase = wg * 128;
  int b = pbase >> 14;
  int tid = threadIdx.x;
  if (tid < 128) al[tid] = a[b * 128 + tid];
  __syncthreads();
  #pragma unroll
  for (int i = 0; i < 8; ++i) {
    int u = i * 256 + tid;
    int p = u >> 4, q = u & 15;
    f16x8 v = *(const f16x8*)&x[((size_t)pbase + p) * 128 + q * 8];
    float sm = 0.f, mx = -1e30f;
    #pragma unroll
    for (int j = 0; j < 8; ++j) {
      float xc = (float)v[j] * al[q * 8 + j];
      sm += xc; mx = fmaxf(mx, xc);
    }
    #pragma unroll
    for (int d = 1; d < 16; d <<= 1) {
      sm += __shfl_xor(sm, d);
      mx = fmaxf(mx, __shfl_xor(mx, d));
    }
    if ((tid & 15) == 0) {
      meanp[pbase + p] = sm * (1.f / 128.f);
      maxp[pbase + p] = mx;
    }
  }
}

// ================= 7x7 spatial-attention conv + sigmoid =================
__global__ __launch_bounds__(256) void k_sa(const float* __restrict__ meanp,
                                            const float* __restrict__ maxp,
                                            const float* __restrict__ sw, const float* __restrict__ sb,
                                            float* __restrict__ sap) {
  __shared__ float lds[2][22][22];
  __shared__ float wl[98];
  int wg = blockIdx.x;             // [b 8][ty 8][tx 8]
  int tx = wg & 7, ty = (wg >> 3) & 7, b = wg >> 6;
  int y0 = ty * 16, x0 = tx * 16;
  int tid = threadIdx.x;
  if (tid < 98) wl[tid] = sw[tid];
  for (int u = tid; u < 2 * 22 * 22; u += 256) {
    int ch = u / 484; int p = u % 484; int py = p / 22, px = p % 22;
    int gy = y0 + py - 3, gx = x0 + px - 3;
    float v = 0.f;
    if (gy >= 0 && gy < 128 && gx >= 0 && gx < 128)
      v = ch ? maxp[(size_t)b * 16384 + gy * 128 + gx] : meanp[(size_t)b * 16384 + gy * 128 + gx];
    lds[ch][py][px] = v;
  }
  __syncthreads();
  int py = tid >> 4, px = tid & 15;
  float accv = sb[0];
  #pragma unroll
  for (int ch = 0; ch < 2; ++ch)
    for (int ky = 0; ky < 7; ++ky)
      #pragma unroll
      for (int kx = 0; kx < 7; ++kx)
        accv += lds[ch][py + ky][px + kx] * wl[ch * 49 + ky * 7 + kx];
  sap[(size_t)b * 16384 + (y0 + py) * 128 + x0 + px] = 1.f / (1.f + expf(-accv));
}

// ================= final: out NCHW = x * a * sa =================
__global__ __launch_bounds__(256) void k_out(const f16* __restrict__ x,
                                             const float* __restrict__ a,
                                             const float* __restrict__ sap,
                                             float* __restrict__ out) {
  __shared__ float lds[32 * 129];
  __shared__ float al[128];
  __shared__ float sl[32];
  int wg = blockIdx.x;
  int pbase = wg * 32; int b = pbase >> 14;
  int tid = threadIdx.x;
  if (tid < 128) al[tid] = a[b * 128 + tid];
  if (tid < 32) sl[tid] = sap[pbase + tid];
  __syncthreads();
  #pragma unroll
  for (int i = 0; i < 2; ++i) {
    int u = i * 256 + tid;
    int p = u >> 4, q = u & 15;
    f16x8 v = *(const f16x8*)&x[((size_t)pbase + p) * 128 + q * 8];
    #pragma unroll
    for (int j = 0; j < 8; ++j) lds[p * 129 + q * 8 + j] = (float)v[j];
  }
  __syncthreads();
  #pragma unroll
  for (int i = 0; i < 16; ++i) {
    int u = i * 256 + tid; int c = u >> 5, p = u & 31;
    float v = lds[p * 129 + c] * al[c] * sl[p];
    out[((size_t)(b * 128 + c)) * 16384 + (pbase & 16383) + p] = v;
  }
}

// ================= launcher =================
extern "C" void kernel_launch(void* const* d_in, const int* in_sizes, int n_in,
                              void* d_out, int out_size, void* d_ws, size_t ws_size,
                              hipStream_t stream) {
  const float* f_high = (const float*)d_in[0];
  const float* f_low  = (const float*)d_in[1];
  const float* off_w1 = (const float*)d_in[2];
  const float* off_b1 = (const float*)d_in[3];
  const float* off_w2 = (const float*)d_in[4];
  const float* off_b2 = (const float*)d_in[5];
  const float* proj_w = (const float*)d_in[6];
  const float* proj_b = (const float*)d_in[7];
  const float* ca_w1  = (const float*)d_in[8];
  const float* ca_b1  = (const float*)d_in[9];
  const float* ca_w2  = (const float*)d_in[10];
  const float* ca_b2  = (const float*)d_in[11];
  const float* sa_w   = (const float*)d_in[12];
  const float* sa_b   = (const float*)d_in[13];
  float* out = (float*)d_out;

  char* ws = (char*)d_ws; size_t o = 0;
  auto alloc = [&](size_t b) { char* p = ws + o; o += (b + 255) & ~(size_t)255; return p; };
  f16*   fhw  = (f16*)alloc(8ull * 4096 * 256 * 2);
  f16*   cat  = (f16*)alloc(8ull * 130 * 130 * 384 * 2);
  f16*   hid  = (f16*)alloc(8ull * 130 * 130 * 64 * 2);
  f16*   offb = (f16*)alloc(8ull * 16384 * 2 * 2);
  f16*   ap1  = (f16*)alloc(221184ull * 2);
  f16*   ap2  = (f16*)alloc(9216ull * 2);
  f16*   pp   = (f16*)alloc(32768ull * 2);
  f16*   xbuf = (f16*)alloc(8ull * 16384 * 128 * 2);
  float* ps   = (float*)alloc(2048ull * 128 * 4);
  float* av   = (float*)alloc(8ull * 128 * 4);
  float* mp   = (float*)alloc(131072ull * 4);
  float* xp   = (float*)alloc(131072ull * 4);
  float* sp   = (float*)alloc(131072ull * 4);

  // prep: pack(864) + pack(36) + packproj(128) + zero(903) + fhw(4096)
  k_prep<<<864 + 36 + 128 + 903 + 4096, 256, 0, stream>>>(off_w1, ap1, off_w2, ap2,
                                                          proj_w, pp, cat, hid, f_high, fhw);
  k_cat<<<1024 + 8192, 256, 0, stream>>>(fhw, f_low, cat);
  k_conv1<<<512, 256, 0, stream>>>(cat, ap1, off_b1, hid);
  k_conv3<64, 1, 2, false, 0, 4><<<512, 256, 0, stream>>>(hid, ap2, off_b2, offb);
  k_gp<<<2048, 256, 0, stream>>>(fhw, offb, pp, proj_b, xbuf, ps);
  k_ca<<<8, 256, 0, stream>>>(ps, ca_w1, ca_b1, ca_w2, ca_b2, av);
  k_sm<<<1024, 256, 0, stream>>>(xbuf, av, mp, xp);
  k_sa<<<512, 256, 0, stream>>>(mp, xp, sa_w, sa_b, sp);
  k_out<<<4096, 256, 0, stream>>>(xbuf, av, sp, out);
}